// Round 1
// 919.942 us; speedup vs baseline: 1.5323x; 1.5323x over previous
//
#include <hip/hip_runtime.h>
#include <hip/hip_bf16.h>
#include <math.h>

typedef __hip_bfloat16 bf16;
typedef unsigned short ushort_t;
typedef unsigned long long ull_t;
typedef __attribute__((ext_vector_type(8))) short short8;
typedef __attribute__((ext_vector_type(4))) float f32x4;

constexpr int NB = 128;      // batch
constexpr int NT = 256;      // time
constexpr int HCAT = 1024;   // 512+256+256
// padded K for bf16 GEMM operands (multiples of 64)
constexpr int KP0 = 320;     // 300
constexpr int KP1 = 128;     // 74
constexpr int KP2 = 64;      // 35

__device__ inline float bf2f(ushort_t u) {
  union { unsigned i; float f; } x; x.i = (unsigned)u << 16; return x.f;
}
__device__ inline ushort_t f2bf(float f) {
  bf16 b = __float2bfloat16(f);
  return *reinterpret_cast<ushort_t*>(&b);
}
// fast sigmoid/tanh via v_exp + v_rcp; saturate correctly at +-inf, no NaN.
__device__ inline float fsig(float x) {
  return __builtin_amdgcn_rcpf(1.f + __expf(-x));
}
__device__ inline float ftanh(float x) {
  return 2.f * __builtin_amdgcn_rcpf(1.f + __expf(-2.f * x)) - 1.f;
}

// ---------------------------------------------------------------------------
// weight convert: fp32 [R][K] -> bf16 [R][KP], zero-padded
// ---------------------------------------------------------------------------
__global__ __launch_bounds__(256) void k_cvt_w(
    const float* __restrict__ in, ushort_t* __restrict__ out, int R, int K, int KP)
{
  int i = blockIdx.x * 256 + threadIdx.x;
  if (i >= R * KP) return;
  int r = i / KP, k = i - r * KP;
  out[i] = (k < K) ? f2bf(in[(size_t)r * K + k]) : (ushort_t)0;
}

// ---------------------------------------------------------------------------
// x convert: fp32 x[B][NT][d] -> bf16 [rows][KP] (row = b*TC+tl), zero-padded
// ---------------------------------------------------------------------------
__global__ __launch_bounds__(256) void k_cvt_x(
    const float* __restrict__ x, ushort_t* __restrict__ out,
    int d, int KP, int t0, int tcShift, int total)
{
  int i = blockIdx.x * 256 + threadIdx.x;
  if (i >= total) return;
  int row = i / KP, k = i - row * KP;
  int b = row >> tcShift, tl = row & ((1 << tcShift) - 1);
  out[i] = (k < d) ? f2bf(x[((size_t)b * NT + t0 + tl) * d + k]) : (ushort_t)0;
}

// ---------------------------------------------------------------------------
// Generic bf16 B^T GEMM (R9-proven): 64x64 tile, BK=64, dbuf LDS, 1 barrier
// per chunk. mode 0: bf16 out + bias0+bias1 (gx). mode 1: fp32 relu (fc1).
// ---------------------------------------------------------------------------
__global__ __launch_bounds__(256) void k_gemm(
    const ushort_t* __restrict__ A, const ushort_t* __restrict__ B, int KP,
    const float* __restrict__ bias0, const float* __restrict__ bias1,
    ushort_t* __restrict__ outb, float* __restrict__ outf, int ldc, int mode)
{
  __shared__ ushort_t As[2][64][72];
  __shared__ ushort_t Bs[2][64][72];
  const int row0 = blockIdx.x * 64;
  const int col0 = blockIdx.y * 64;
  const int tid  = threadIdx.x;
  const int lane = tid & 63;
  const int w    = tid >> 6;
  const int n    = lane & 15;
  const int quad = lane >> 4;
  const int sr = tid >> 2;           // staging row 0..63
  const int sc = (tid & 3) * 16;     // staging col (elems)

  const ushort_t* arow = A + (size_t)(row0 + sr) * KP + sc;
  const ushort_t* brow = B + (size_t)(col0 + sr) * KP + sc;

  short8 ra0 = *reinterpret_cast<const short8*>(arow);
  short8 ra1 = *reinterpret_cast<const short8*>(arow + 8);
  short8 rb0 = *reinterpret_cast<const short8*>(brow);
  short8 rb1 = *reinterpret_cast<const short8*>(brow + 8);
  *reinterpret_cast<short8*>(&As[0][sr][sc])     = ra0;
  *reinterpret_cast<short8*>(&As[0][sr][sc + 8]) = ra1;
  *reinterpret_cast<short8*>(&Bs[0][sr][sc])     = rb0;
  *reinterpret_cast<short8*>(&Bs[0][sr][sc + 8]) = rb1;

  f32x4 acc[4] = {{0,0,0,0},{0,0,0,0},{0,0,0,0},{0,0,0,0}};
  const int nch = KP >> 6;
  for (int ch = 0; ch < nch; ++ch) {
    __syncthreads();
    const int cur = ch & 1;
    if (ch + 1 < nch) {
      const ushort_t* an = arow + (ch + 1) * 64;
      const ushort_t* bn = brow + (ch + 1) * 64;
      ra0 = *reinterpret_cast<const short8*>(an);
      ra1 = *reinterpret_cast<const short8*>(an + 8);
      rb0 = *reinterpret_cast<const short8*>(bn);
      rb1 = *reinterpret_cast<const short8*>(bn + 8);
    }
#pragma unroll
    for (int kc = 0; kc < 2; ++kc) {
      short8 bfr = *reinterpret_cast<const short8*>(&Bs[cur][w * 16 + n][quad * 8 + kc * 32]);
#pragma unroll
      for (int mt = 0; mt < 4; ++mt) {
        short8 afr = *reinterpret_cast<const short8*>(&As[cur][mt * 16 + n][quad * 8 + kc * 32]);
        acc[mt] = __builtin_amdgcn_mfma_f32_16x16x32_bf16(afr, bfr, acc[mt], 0, 0, 0);
      }
    }
    if (ch + 1 < nch) {
      const int nxt = 1 - cur;
      *reinterpret_cast<short8*>(&As[nxt][sr][sc])     = ra0;
      *reinterpret_cast<short8*>(&As[nxt][sr][sc + 8]) = ra1;
      *reinterpret_cast<short8*>(&Bs[nxt][sr][sc])     = rb0;
      *reinterpret_cast<short8*>(&Bs[nxt][sr][sc + 8]) = rb1;
    }
  }

  const int col = col0 + w * 16 + n;
  if (mode == 0) {
    const float bsum = bias0[col] + bias1[col];
#pragma unroll
    for (int mt = 0; mt < 4; ++mt)
#pragma unroll
      for (int r = 0; r < 4; ++r) {
        int row = row0 + mt * 16 + quad * 4 + r;
        outb[(size_t)row * ldc + col] = f2bf(acc[mt][r] + bsum);
      }
  } else {
    const float bsum = bias0[col];
#pragma unroll
    for (int mt = 0; mt < 4; ++mt)
#pragma unroll
      for (int r = 0; r < 4; ++r) {
        int row = row0 + mt * 16 + quad * 4 + r;
        outf[(size_t)row * ldc + col] = fmaxf(acc[mt][r] + bsum, 0.f);
      }
  }
}

// ---------------------------------------------------------------------------
// fc2 + log_softmax: one wave per chunk row; map chunk row -> global (b,t)
// ---------------------------------------------------------------------------
__global__ __launch_bounds__(256) void k_fc2(
    const float* __restrict__ Z, const float* __restrict__ W2,
    const float* __restrict__ b2, float* __restrict__ out, int t0, int tcShift)
{
  const int wave = threadIdx.x >> 6;
  const int lane = threadIdx.x & 63;
  const int bt = blockIdx.x * 4 + wave;
  const float* z = Z + (size_t)bt * 256;
  float zv[4];
#pragma unroll
  for (int j = 0; j < 4; ++j) zv[j] = z[lane + 64 * j];
  float lg[7];
#pragma unroll
  for (int o = 0; o < 7; ++o) {
    float a = 0.f;
#pragma unroll
    for (int j = 0; j < 4; ++j) a += zv[j] * W2[o * 256 + lane + 64 * j];
#pragma unroll
    for (int off = 32; off > 0; off >>= 1) a += __shfl_down(a, off, 64);
    lg[o] = a;   // valid on lane 0
  }
  if (lane == 0) {
    const int b = bt >> tcShift;
    const int tl = bt & ((1 << tcShift) - 1);
    float* op = out + ((size_t)b * NT + t0 + tl) * 7;
    float lo[7];
    float m = -1e30f;
#pragma unroll
    for (int o = 0; o < 7; ++o) { lo[o] = lg[o] + b2[o]; m = fmaxf(m, lo[o]); }
    float s = 0.f;
#pragma unroll
    for (int o = 0; o < 7; ++o) s += expf(lo[o] - m);
    float lse = m + logf(s);
#pragma unroll
    for (int o = 0; o < 7; ++o) op[o] = lo[o] - lse;
  }
}

// ---------------------------------------------------------------------------
// Recurrent kernel R11: epoch-packed h exchange.
// h is published as u32 words: (global_step_epoch << 16) | bf16(h).
// The data word IS the readiness flag:
//  - no vmcnt drain before a flag store (no flag at all)
//  - no separate flag publish / poll LLC round trips and no hot flag line
//  - the poll load that observes freshness already carries the h payload
// Double buffer by step parity keeps old-epoch words distinguishable.
// Barriers per step: 2 (htile ready, gbuf ready) instead of 4.
// ---------------------------------------------------------------------------
template<int HL>
__device__ void lstm_body(const float* __restrict__ Whh,
                          const ushort_t* __restrict__ gx,   // bf16 bits, [NB][TC][4*HL]
                          unsigned* __restrict__ hb2,        // u32 [2][NB][HCAT] = epoch|bf16
                          float* __restrict__ cbuf,          // fp32 [NB][HCAT]
                          ushort_t* __restrict__ hs,         // bf16 [NB][TC][HCAT]
                          ushort_t* htile,                   // LDS [16][HL+8]
                          float (*gbuf)[16][34],             // LDS gate tiles
                          int g, int u0, int hoff, int t0, int TC)
{
  constexpr int KC  = HL / 32;
  constexpr int LHP = HL + 8;          // padded LDS row, bf16 units
  constexpr int NGR = HL / 32;         // 8-byte source granules per thread
  const int tid  = threadIdx.x;
  const int lane = tid & 63;
  const int wgate = tid >> 6;          // wave index == gate (i,f,g,o)
  const int n    = lane & 15;
  const int quad = lane >> 4;

  short8 wfrag[2][KC];
#pragma unroll
  for (int tau = 0; tau < 2; ++tau) {
    const float* wrow = Whh + ((size_t)wgate * HL + u0 + 16 * tau + n) * HL + quad * 8;
#pragma unroll
    for (int kc = 0; kc < KC; ++kc) {
      short8 f;
#pragma unroll
      for (int j = 0; j < 8; ++j) f[j] = (short)f2bf(wrow[kc * 32 + j]);
      wfrag[tau][kc] = f;
    }
  }

  const int u  = tid & 31;
  const int bh = tid >> 5;             // 0..7
  const int bb0 = g * 16 + bh;
  const int bb1 = bb0 + 8;
  const int hcol = hoff + u0 + u;
  float c0 = cbuf[(size_t)bb0 * HCAT + hcol];
  float c1 = cbuf[(size_t)bb1 * HCAT + hcol];

  const int srow = wgate * 4 + (lane >> 4);   // 0..15
  const int scol = lane & 15;
  unsigned* htile32 = reinterpret_cast<unsigned*>(htile);

  const size_t G4 = (size_t)(4 * HL);
  float gxv0[4], gxv1[4];
#pragma unroll
  for (int q = 0; q < 4; ++q) {
    gxv0[q] = bf2f(gx[((size_t)bb0 * TC) * G4 + (size_t)q * HL + u0 + u]);
    gxv1[q] = bf2f(gx[((size_t)bb1 * TC) * G4 + (size_t)q * HL + u0 + u]);
  }

  const ull_t EPM = 0xFFFF0000FFFF0000ull;

  for (int t = 0; t < TC; ++t) {
    const unsigned ep = (unsigned)(t0 + t);
    const ull_t want = ((ull_t)ep << 16) | ((ull_t)ep << 48);
    const ull_t* src64 = reinterpret_cast<const ull_t*>(
        hb2 + ((size_t)(ep & 1) * NB + g * 16 + srow) * HCAT + hoff);

    // per-thread poll: loads return payload+epoch together; a sweep issues all
    // NGR loads back-to-back (waits batched), so one sweep costs ~1 LLC latency
    ull_t vv[NGR];
    while (true) {
#pragma unroll
      for (int i = 0; i < NGR; ++i)
        vv[i] = __hip_atomic_load(src64 + scol + i * 16,
                                  __ATOMIC_RELAXED, __HIP_MEMORY_SCOPE_AGENT);
      ull_t bad = 0;
#pragma unroll
      for (int i = 0; i < NGR; ++i) bad |= (vv[i] ^ want) & EPM;
      if (bad == 0) break;
      __builtin_amdgcn_s_sleep(1);
    }
#pragma unroll
    for (int i = 0; i < NGR; ++i)
      htile32[srow * (LHP / 2) + scol + i * 16] =
          (unsigned)(vv[i] & 0xffffu) | ((unsigned)(vv[i] >> 16) & 0xffff0000u);
    __syncthreads();   // htile complete (also orders prev-step gbuf reads vs writes)

    f32x4 acc0 = {0.f, 0.f, 0.f, 0.f};
    f32x4 acc1 = {0.f, 0.f, 0.f, 0.f};
#pragma unroll
    for (int kc = 0; kc < KC; ++kc) {
      short8 a = *reinterpret_cast<const short8*>(htile + n * LHP + quad * 8 + kc * 32);
      acc0 = __builtin_amdgcn_mfma_f32_16x16x32_bf16(a, wfrag[0][kc], acc0, 0, 0, 0);
      acc1 = __builtin_amdgcn_mfma_f32_16x16x32_bf16(a, wfrag[1][kc], acc1, 0, 0, 0);
    }
#pragma unroll
    for (int r = 0; r < 4; ++r) {
      gbuf[wgate][quad * 4 + r][n]      = acc0[r];
      gbuf[wgate][quad * 4 + r][16 + n] = acc1[r];
    }
    __syncthreads();   // gbuf ready (also ensures all htile reads done)

    float pi0 = gbuf[0][bh][u] + gxv0[0];
    float pf0 = gbuf[1][bh][u] + gxv0[1];
    float pg0 = gbuf[2][bh][u] + gxv0[2];
    float po0 = gbuf[3][bh][u] + gxv0[3];
    float pi1 = gbuf[0][bh + 8][u] + gxv1[0];
    float pf1 = gbuf[1][bh + 8][u] + gxv1[1];
    float pg1 = gbuf[2][bh + 8][u] + gxv1[2];
    float po1 = gbuf[3][bh + 8][u] + gxv1[3];

    float si0 = fsig(pi0), sf0 = fsig(pf0), so0 = fsig(po0);
    float tg0 = ftanh(pg0);
    c0 = sf0 * c0 + si0 * tg0;
    float h0 = so0 * ftanh(c0);
    float si1 = fsig(pi1), sf1 = fsig(pf1), so1 = fsig(po1);
    float tg1 = ftanh(pg1);
    c1 = sf1 * c1 + si1 * tg1;
    float h1 = so1 * ftanh(c1);

    // publish h(t+1): payload and validity in one atomic 4B word — no fence,
    // no drain, no flag. Issued immediately; everything after is off-path.
    const ushort_t hb0 = f2bf(h0), hb1 = f2bf(h1);
    const unsigned ep1 = (ep + 1) << 16;
    unsigned* nxt = hb2 + (size_t)((ep + 1) & 1) * NB * HCAT;
    __hip_atomic_store(nxt + (size_t)bb0 * HCAT + hcol, ep1 | (unsigned)hb0,
                       __ATOMIC_RELAXED, __HIP_MEMORY_SCOPE_AGENT);
    __hip_atomic_store(nxt + (size_t)bb1 * HCAT + hcol, ep1 | (unsigned)hb1,
                       __ATOMIC_RELAXED, __HIP_MEMORY_SCOPE_AGENT);

    // off-critical-path: hs stores + gx(t+1) prefetch
    hs[((size_t)bb0 * TC + t) * HCAT + hcol] = hb0;
    hs[((size_t)bb1 * TC + t) * HCAT + hcol] = hb1;
    if (t + 1 < TC) {
#pragma unroll
      for (int q = 0; q < 4; ++q) {
        gxv0[q] = bf2f(gx[((size_t)bb0 * TC + t + 1) * G4 + (size_t)q * HL + u0 + u]);
        gxv1[q] = bf2f(gx[((size_t)bb1 * TC + t + 1) * G4 + (size_t)q * HL + u0 + u]);
      }
    }
  }
  cbuf[(size_t)bb0 * HCAT + hcol] = c0;
  cbuf[(size_t)bb1 * HCAT + hcol] = c1;
}

__global__ __launch_bounds__(256, 1) void k_lstm(
    const float* __restrict__ Whh0, const float* __restrict__ Whh1,
    const float* __restrict__ Whh2,
    const ushort_t* __restrict__ gx0, const ushort_t* __restrict__ gx1,
    const ushort_t* __restrict__ gx2,
    unsigned* __restrict__ hb2, float* __restrict__ cbuf,
    ushort_t* __restrict__ hs,
    int t0, int TC)
{
  __shared__ ushort_t htile[16 * 520];
  __shared__ float gbuf[4][16][34];
  const int g    = blockIdx.x & 7;
  const int rank = blockIdx.x >> 3;        // 0..31
  if (rank < 16) {
    lstm_body<512>(Whh0, gx0, hb2, cbuf, hs, htile, gbuf,
                   g, rank * 32, 0, t0, TC);
  } else if (rank < 24) {
    lstm_body<256>(Whh1, gx1, hb2, cbuf, hs, htile, gbuf,
                   g, (rank - 16) * 32, 512, t0, TC);
  } else {
    lstm_body<256>(Whh2, gx2, hb2, cbuf, hs, htile, gbuf,
                   g, (rank - 24) * 32, 768, t0, TC);
  }
}

// fallback if workspace is too small: distinctive sentinel
__global__ void k_fill(float* __restrict__ out, int n, float v) {
  int i = blockIdx.x * 256 + threadIdx.x;
  if (i < n) out[i] = v;
}

extern "C" void kernel_launch(void* const* d_in, const int* in_sizes, int n_in,
                              void* d_out, int out_size, void* d_ws, size_t ws_size,
                              hipStream_t stream) {
  (void)in_sizes; (void)n_in;
  const float* x0  = (const float*)d_in[0];
  const float* x1  = (const float*)d_in[1];
  const float* x2  = (const float*)d_in[2];
  const float* Wih0 = (const float*)d_in[3];
  const float* Whh0 = (const float*)d_in[4];
  const float* bih0 = (const float*)d_in[5];
  const float* bhh0 = (const float*)d_in[6];
  const float* Wih1 = (const float*)d_in[7];
  const float* Whh1 = (const float*)d_in[8];
  const float* bih1 = (const float*)d_in[9];
  const float* bhh1 = (const float*)d_in[10];
  const float* Wih2 = (const float*)d_in[11];
  const float* Whh2 = (const float*)d_in[12];
  const float* bih2 = (const float*)d_in[13];
  const float* bhh2 = (const float*)d_in[14];
  const float* W1 = (const float*)d_in[15];
  const float* b1 = (const float*)d_in[16];
  const float* W2 = (const float*)d_in[17];
  const float* b2 = (const float*)d_in[18];
  float* out = (float*)d_out;

  const size_t szHbuf  = (size_t)2 * NB * HCAT * 4;   // u32 epoch|bf16, dbuf
  const size_t szCbuf  = (size_t)NB * HCAT * 4;
  const size_t szWb0   = (size_t)2048 * KP0 * 2;
  const size_t szWb1   = (size_t)1024 * KP1 * 2;
  const size_t szWb2   = (size_t)1024 * KP2 * 2;
  const size_t szW1b   = (size_t)256 * 1024 * 2;

  const int cands[6] = {256, 128, 64, 32, 16, 8};
  int TC = 0;
  for (int ci = 0; ci < 6; ++ci) {
    int tc = cands[ci];
    size_t rows = (size_t)NB * tc;
    size_t o = 0;
    auto al = [&](size_t bytes) { o += (bytes + 255) & ~(size_t)255; };
    al(szHbuf); al(szCbuf);
    al(szWb0); al(szWb1); al(szWb2); al(szW1b);
    al(rows * HCAT * 2);                // hs chunk
    al(rows * 256 * 4);                 // z chunk
    al(rows * 2048 * 2);                // gx0 chunk
    al(rows * 1024 * 2);                // gx1 chunk
    al(rows * 1024 * 2);                // gx2 chunk
    al(rows * KP0 * 2);                 // xb0
    al(rows * KP1 * 2);                 // xb1
    al(rows * KP2 * 2);                 // xb2
    if (o <= ws_size) { TC = tc; break; }
  }
  if (TC == 0) {
    k_fill<<<dim3((out_size + 255) / 256), dim3(256), 0, stream>>>(out, out_size, -8888.f);
    return;
  }
  const int tcShift = __builtin_ctz(TC);
  const size_t rows = (size_t)NB * TC;

  char* ws = (char*)d_ws;
  size_t off = 0;
  auto alloc = [&](size_t bytes) -> void* {
    void* p = ws + off;
    off += (bytes + 255) & ~(size_t)255;
    return p;
  };
  unsigned* hb2  = (unsigned*)alloc(szHbuf);
  float* cbuf    = (float*)alloc(szCbuf);
  size_t staticEnd = off;
  ushort_t* wb0  = (ushort_t*)alloc(szWb0);
  ushort_t* wb1  = (ushort_t*)alloc(szWb1);
  ushort_t* wb2  = (ushort_t*)alloc(szWb2);
  ushort_t* w1b  = (ushort_t*)alloc(szW1b);
  ushort_t* hs   = (ushort_t*)alloc(rows * HCAT * 2);
  float* z       = (float*)alloc(rows * 256 * 4);
  ushort_t* gx0  = (ushort_t*)alloc(rows * 2048 * 2);
  ushort_t* gx1  = (ushort_t*)alloc(rows * 1024 * 2);
  ushort_t* gx2  = (ushort_t*)alloc(rows * 1024 * 2);
  ushort_t* xb0  = (ushort_t*)alloc(rows * KP0 * 2);
  ushort_t* xb1  = (ushort_t*)alloc(rows * KP1 * 2);
  ushort_t* xb2  = (ushort_t*)alloc(rows * KP2 * 2);

  hipMemsetAsync(ws, 0, staticEnd, stream);   // epoch 0 == h(0) == 0, c(0) == 0

  dim3 blk(256);
  k_cvt_w<<<dim3((2048 * KP0 + 255) / 256), blk, 0, stream>>>(Wih0, wb0, 2048, 300, KP0);
  k_cvt_w<<<dim3((1024 * KP1 + 255) / 256), blk, 0, stream>>>(Wih1, wb1, 1024, 74, KP1);
  k_cvt_w<<<dim3((1024 * KP2 + 255) / 256), blk, 0, stream>>>(Wih2, wb2, 1024, 35, KP2);
  k_cvt_w<<<dim3((256 * 1024 + 255) / 256), blk, 0, stream>>>(W1, w1b, 256, 1024, 1024);

  const int rb = (int)(rows / 64);   // row-blocks per chunk
  for (int t0 = 0; t0 < NT; t0 += TC) {
    int tot0 = (int)(rows * KP0), tot1 = (int)(rows * KP1), tot2 = (int)(rows * KP2);
    k_cvt_x<<<dim3((tot0 + 255) / 256), blk, 0, stream>>>(x0, xb0, 300, KP0, t0, tcShift, tot0);
    k_cvt_x<<<dim3((tot1 + 255) / 256), blk, 0, stream>>>(x1, xb1, 74, KP1, t0, tcShift, tot1);
    k_cvt_x<<<dim3((tot2 + 255) / 256), blk, 0, stream>>>(x2, xb2, 35, KP2, t0, tcShift, tot2);

    k_gemm<<<dim3(rb, 2048 / 64), blk, 0, stream>>>(xb0, wb0, KP0, bih0, bhh0, gx0, nullptr, 2048, 0);
    k_gemm<<<dim3(rb, 1024 / 64), blk, 0, stream>>>(xb1, wb1, KP1, bih1, bhh1, gx1, nullptr, 1024, 0);
    k_gemm<<<dim3(rb, 1024 / 64), blk, 0, stream>>>(xb2, wb2, KP2, bih2, bhh2, gx2, nullptr, 1024, 0);

    k_lstm<<<dim3(256), blk, 0, stream>>>(Whh0, Whh1, Whh2,
                                          gx0, gx1, gx2,
                                          hb2, cbuf, hs, t0, TC);

    k_gemm<<<dim3(rb, 256 / 64), blk, 0, stream>>>(hs, w1b, 1024, b1, nullptr, nullptr, z, 256, 1);
    k_fc2<<<dim3((int)(rows / 4)), blk, 0, stream>>>(z, W2, b2, out, t0, tcShift);
  }
}